// Round 4
// baseline (1012.458 us; speedup 1.0000x reference)
//
#include <hip/hip_runtime.h>
#include <hip/hip_bf16.h>
#include <hip/hip_cooperative_groups.h>
#include <stdint.h>

namespace cg = cooperative_groups;

// ---------------------------------------------------------------------------
// GraphAttentionLayer: out = softmax(lrelu(s1_i + s2_j)) @ h,  h = x @ W^T
// Round 7: launch-overhead attack (~20-25us per launch measured by ledger).
//  - 8 launches -> 3: cvt(merged) + gemm + ONE cooperative kernel holding
//    {panel-reduce, rankcount, mega, pass1+scatter, boff, pass2} with 5
//    grid.sync()s.
//  - GEMM epilogue: s1/s2 atomics (L2 same-line serialization, +48us, +16MB
//    WRITE_SIZE) replaced by plain per-panel-quarter partial stores
//    s1p/s2p[64][8192] (alias Bct/Cct), reduced in the coop kernel.
// ---------------------------------------------------------------------------

typedef float  f32x4  __attribute__((ext_vector_type(4)));
typedef __bf16 bf16x8 __attribute__((ext_vector_type(8)));

#define AS1 __attribute__((address_space(1)))
#define AS3 __attribute__((address_space(3)))

constexpr int NB  = 8192;    // batch rows (i and j)
constexpr int DF  = 4096;    // feature dim
constexpr int CH  = 64;      // sweep chunk length
constexpr int NCH = NB / CH; // 128

constexpr int GK  = DF;      // GEMM K
constexpr int BKK = 64;      // GEMM K-tile
constexpr int NT2 = GK / BKK;

__device__ __forceinline__ uint16_t f2bf_u(float f) {   // RNE fp32 -> bf16
  union { float f; uint32_t u; } x; x.f = f;
  return (uint16_t)((x.u + 0x7FFFu + ((x.u >> 16) & 1u)) >> 16);
}
__device__ __forceinline__ float bfu2f(uint16_t v) {
  union { uint32_t u; float f; } x; x.u = ((uint32_t)v) << 16;
  return x.f;
}

// --------------------------- fp32 -> bf16 convert (x and W in one) ----------
__global__ __launch_bounds__(256) void cvt_all(
    const float* __restrict__ x, uint16_t* __restrict__ xb,
    const float* __restrict__ W, uint16_t* __restrict__ Wb) {
  const int idx = blockIdx.x * 256 + threadIdx.x;
  const int stride = gridDim.x * 256;
  const int n4x = (NB * DF) / 4, n4w = (DF * DF) / 4;
  for (int i = idx; i < n4x; i += stride) {
    float4 v = ((const float4*)x)[i];
    ushort4 o;
    o.x = f2bf_u(v.x); o.y = f2bf_u(v.y); o.z = f2bf_u(v.z); o.w = f2bf_u(v.w);
    ((ushort4*)xb)[i] = o;
  }
  for (int i = idx; i < n4w; i += stride) {
    float4 v = ((const float4*)W)[i];
    ushort4 o;
    o.x = f2bf_u(v.x); o.y = f2bf_u(v.y); o.z = f2bf_u(v.z); o.w = f2bf_u(v.w);
    ((ushort4*)Wb)[i] = o;
  }
}

// --------------------------- NT bf16 GEMM: async dbuf + s12 partials --------
// C[M=8192][N=4096] = A[8192][4096] * B[4096][4096]^T, bf16 in/out, fp32 acc.
// Epilogue: per-panel-quarter partial dots s1p/s2p[q=bx*4+wn][row] (plain
// stores, no atomics).

#define STAGE_A(tt, half) do {                                                 \
  const uint16_t* g0_ = Ag + (size_t)((half) * 128) * GK + (size_t)(tt) * BKK; \
  uint32_t d_ = ((uint32_t)((tt) & 1)) * 32768u + (uint32_t)(half) * 8192u +   \
                (uint32_t)wave * 512u;                                         \
  __builtin_amdgcn_global_load_lds((const AS1 void*)g0_,                       \
      (AS3 void*)(lds + d_), 16, 0, 0);                                        \
  __builtin_amdgcn_global_load_lds((const AS1 void*)(g0_ + (size_t)64 * GK),   \
      (AS3 void*)(lds + d_ + 4096u), 16, 0, 0);                                \
} while (0)

#define STAGE_B(tt, half) do {                                                 \
  const uint16_t* g0_ = Bg + (size_t)((half) * 128) * GK + (size_t)(tt) * BKK; \
  uint32_t d_ = ((uint32_t)((tt) & 1)) * 32768u + 16384u +                     \
                (uint32_t)(half) * 8192u + (uint32_t)wave * 512u;              \
  __builtin_amdgcn_global_load_lds((const AS1 void*)g0_,                       \
      (AS3 void*)(lds + d_), 16, 0, 0);                                        \
  __builtin_amdgcn_global_load_lds((const AS1 void*)(g0_ + (size_t)64 * GK),   \
      (AS3 void*)(lds + d_ + 4096u), 16, 0, 0);                                \
} while (0)

#define LDA(mh) do {                                                           \
  _Pragma("unroll") for (int mf = 0; mf < 4; ++mf)                             \
    _Pragma("unroll") for (int ks = 0; ks < 2; ++ks)                           \
      aF[mf][ks] = *(const bf16x8*)(lds + bufo +                               \
          (uint32_t)(wm * 128 + (mh) * 64 + mf * 16 + lr) * 64u +              \
          (uint32_t)((ks * 32 + lg * 8) ^ swl));                               \
} while (0)

#define LDB(nh) do {                                                           \
  _Pragma("unroll") for (int nf = 0; nf < 2; ++nf)                             \
    _Pragma("unroll") for (int ks = 0; ks < 2; ++ks)                           \
      bF[nf][ks] = *(const bf16x8*)(lds + bufo + 16384u +                      \
          (uint32_t)(wn * 64 + (nh) * 32 + nf * 16 + lr) * 64u +               \
          (uint32_t)((ks * 32 + lg * 8) ^ swl));                               \
} while (0)

#define MMA(mh, nh) do {                                                       \
  _Pragma("unroll") for (int ks = 0; ks < 2; ++ks)                             \
    _Pragma("unroll") for (int mf = 0; mf < 4; ++mf)                           \
      _Pragma("unroll") for (int nf = 0; nf < 2; ++nf)                         \
        acc[(mh) * 4 + mf][(nh) * 2 + nf] =                                    \
            __builtin_amdgcn_mfma_f32_16x16x32_bf16(aF[mf][ks], bF[nf][ks],    \
                acc[(mh) * 4 + mf][(nh) * 2 + nf], 0, 0, 0);                   \
} while (0)

__global__ __launch_bounds__(512, 2) void gemm_nt_async(
    const uint16_t* __restrict__ A, const uint16_t* __restrict__ B,
    uint16_t* __restrict__ C, const float* __restrict__ a,
    float* __restrict__ s1p, float* __restrict__ s2p) {
  __shared__ uint16_t lds[65536];   // 128 KiB: [buf][A|B][256*64]

  const int tid  = threadIdx.x;
  const int wave = tid >> 6;
  const int lane = tid & 63;
  const int lr   = lane & 15;
  const int lg   = lane >> 4;        // 0..3
  const int wm   = wave >> 2;        // 0..1  (M half)
  const int wn   = wave & 3;         // 0..3  (N quarter)
  const int swl  = (lr & 7) << 3;    // read-side XOR swizzle (elements)

  // XCD-aware bijective swizzle over 512 blocks (512 % 8 == 0)
  const int bid = blockIdx.x;
  const int swz = (bid & 7) * 64 + (bid >> 3);
  const int bx  = swz & 15;          // N tile (16)
  const int by  = swz >> 4;          // M tile (32)
  const int rowBase = by * 256;
  const int colBase = bx * 256;

  // stage source: thread t covers LDS row sr, 16-B chunk (t&7); source chunk
  // is pre-swizzled so that linear LDS dest + swizzled read = identity.
  const int sr  = tid >> 3;                    // 0..63
  const int sch = (tid & 7) ^ (sr & 7);
  const uint16_t* Ag = A + (size_t)(rowBase + sr) * GK + sch * 8;
  const uint16_t* Bg = B + (size_t)(colBase + sr) * GK + sch * 8;

  f32x4 acc[8][4];
#pragma unroll
  for (int mf = 0; mf < 8; ++mf)
#pragma unroll
    for (int nf = 0; nf < 4; ++nf) acc[mf][nf] = (f32x4){0.f, 0.f, 0.f, 0.f};

  // prologue: stage tile 0 -> buf0, wait, sync
  STAGE_A(0, 0);
  STAGE_A(0, 1);
  STAGE_B(0, 0);
  STAGE_B(0, 1);
  asm volatile("s_waitcnt vmcnt(0)" ::: "memory");
  __builtin_amdgcn_s_barrier();

  bf16x8 aF[4][2], bF[2][2];

  for (int t = 0; t < NT2; ++t) {
    const uint32_t bufo = ((uint32_t)(t & 1)) * 32768u;

    // prefetch next tile -> OTHER buffer (never touches buffer being read)
    if (t + 1 < NT2) {
      STAGE_A(t + 1, 0);
      STAGE_A(t + 1, 1);
      STAGE_B(t + 1, 0);
      STAGE_B(t + 1, 1);
    }

    LDA(0); LDB(0);
    MMA(0, 0);
    LDB(1);
    MMA(0, 1);
    LDA(1);
    MMA(1, 1);
    LDB(0);          // re-read B-half0 (cheaper than +16 live VGPRs)
    MMA(1, 0);

    if (t + 1 < NT2) {
      asm volatile("s_waitcnt vmcnt(0)" ::: "memory");
      __builtin_amdgcn_s_barrier();
    }
  }

  // epilogue: C/D layout col = lane&15, row = (lane>>4)*4 + reg
  const int r0 = rowBase + wm * 128 + lg * 4;
  const int c0 = colBase + wn * 64 + lr;
#pragma unroll
  for (int mf = 0; mf < 8; ++mf)
#pragma unroll
    for (int nf = 0; nf < 4; ++nf)
#pragma unroll
      for (int e = 0; e < 4; ++e)
        C[(size_t)(r0 + mf * 16 + e) * (size_t)DF + (c0 + nf * 16)] =
            f2bf_u(acc[mf][nf][e]);

  // ---- s12 partials: quarter q = bx*4 + wn covers cols [q*64, q*64+64) ----
  float a1v[4], a2v[4];
#pragma unroll
  for (int nf = 0; nf < 4; ++nf) {
    int col = c0 + nf * 16;
    a1v[nf] = a[col];
    a2v[nf] = a[DF + col];
  }
  const int q = bx * 4 + wn;
#pragma unroll
  for (int mf = 0; mf < 8; ++mf) {
#pragma unroll
    for (int e = 0; e < 4; ++e) {
      float p1 = 0.f, p2 = 0.f;
#pragma unroll
      for (int nf = 0; nf < 4; ++nf) {
        float hv = acc[mf][nf][e];
        p1 += hv * a1v[nf];
        p2 += hv * a2v[nf];
      }
      p1 += __shfl_xor(p1, 1, 64); p1 += __shfl_xor(p1, 2, 64);
      p1 += __shfl_xor(p1, 4, 64); p1 += __shfl_xor(p1, 8, 64);
      p2 += __shfl_xor(p2, 1, 64); p2 += __shfl_xor(p2, 2, 64);
      p2 += __shfl_xor(p2, 4, 64); p2 += __shfl_xor(p2, 8, 64);
      if (lr == 0) {
        int row = r0 + mf * 16 + e;
        s1p[(size_t)q * NB + row] = p1;
        s2p[(size_t)q * NB + row] = p2;
      }
    }
  }
}

// --------------------------- cooperative post kernel ------------------------
// 512 blocks x 256 threads, phases separated by grid.sync():
//  A0: s1/s2 = sum over 64 panel-quarters of s1p/s2p         (32 blocks)
//  A : rank+count, 16-way j-split                            (512 blocks)
//  B : scan + finalize + bucket_scan (LDS hist)              (block 0)
//  C : pass1 chunk totals + fused scatter                    (512 blocks)
//  D : per-column chunk-offset scan                          (64 blocks)
//  E : pass2 sweep + direct emission                         (512 blocks)

struct PostArgs {
  const uint16_t* h;
  const float* s1p; const float* s2p;
  float* s1; float* s2;
  int* pi; float* s2sorted; int* ci;
  float* Sb; float* Sc; float* wbg; float* wcg;
  float* f1; float* f2;
  int* istart; int* cursor; int* ilist;
  float* Bct; float* Cct; float* Boff; float* Coff;
  float* out;
};

union PostSmem {
  float ld[NB];                                                      // A
  struct { float pb[256]; float pc[256]; int histL[NB + 1]; int ps[256]; } mg; // B
  struct { int pj[CH]; float wb[CH]; float wc[CH]; int se[CH + 2]; } pp;       // C,E
  struct { float sB[4][64]; float sC[4][64]; } bo;                   // D
};

__global__ __launch_bounds__(256, 2) void gat_post(PostArgs P) {
  __shared__ PostSmem smu;
  cg::grid_group grid = cg::this_grid();
  const int bid = blockIdx.x;
  const int t   = threadIdx.x;

  // ---------------- A0: reduce panel partials -> s1, s2 ----------------
  if (bid < 32) {
    const int i = bid * 256 + t;
    float v1 = 0.f, v2 = 0.f;
#pragma unroll 16
    for (int q = 0; q < 64; q++) {
      v1 += P.s1p[(size_t)q * NB + i];
      v2 += P.s2p[(size_t)q * NB + i];
    }
    P.s1[i] = v1;
    P.s2[i] = v2;
  }
  grid.sync();

  // ---------------- A: rank + count (16-way j-split) ----------------
  {
    for (int idx = t; idx < NB; idx += 256) smu.ld[idx] = P.s2[idx];
    __syncthreads();
    const int i    = bid * 16 + (t >> 4);
    const int part = t & 15;
    const float v   = smu.ld[i];
    const float thr = -P.s1[i];
    int cr = 0, cc = 0;
    const int q0 = part * (NB / 64);   // float4 units, 128 per part
    for (int q = q0; q < q0 + NB / 64; q++) {
      float4 u = ((const float4*)smu.ld)[q];
      int jj = q * 4;
      cr += (u.x > v) || (u.x == v && (jj + 0) < i);
      cr += (u.y > v) || (u.y == v && (jj + 1) < i);
      cr += (u.z > v) || (u.z == v && (jj + 2) < i);
      cr += (u.w > v) || (u.w == v && (jj + 3) < i);
      cc += (u.x > thr) + (u.y > thr) + (u.z > thr) + (u.w > thr);
    }
    cr += __shfl_xor(cr, 1, 64); cr += __shfl_xor(cr, 2, 64);
    cr += __shfl_xor(cr, 4, 64); cr += __shfl_xor(cr, 8, 64);
    cc += __shfl_xor(cc, 1, 64); cc += __shfl_xor(cc, 2, 64);
    cc += __shfl_xor(cc, 4, 64); cc += __shfl_xor(cc, 8, 64);
    if (part == 0) {
      P.pi[cr] = i;
      P.s2sorted[cr] = v;
      P.ci[i] = cc;
    }
  }
  grid.sync();

  // ---------------- B: scan + finalize + bucket_scan (block 0) ----------------
  if (bid == 0) {
    for (int g = t; g <= NB; g += 256) smu.mg.histL[g] = 0;
    float sb = 0.f, sc = 0.f;
    for (int c = t * 32; c < t * 32 + 32; c++) {
      float s = P.s2sorted[c];
      float wb = __expf(0.2f * s), wc = __expf(s);
      P.wbg[c] = wb; P.wcg[c] = wc;
      sb += wb; sc += wc;
    }
    smu.mg.pb[t] = sb; smu.mg.pc[t] = sc;
    __syncthreads();
    if (t == 0) {
      float rb = 0.f, rc = 0.f;
      for (int q = 0; q < 256; q++) {
        float tb = smu.mg.pb[q], tc = smu.mg.pc[q];
        smu.mg.pb[q] = rb; smu.mg.pc[q] = rc;
        rb += tb; rc += tc;
      }
      P.Sb[0] = 0.f; P.Sc[0] = 0.f;
      P.Sb[NB] = rb; P.Sc[NB] = rc;
    }
    __syncthreads();
    {
      float rb = smu.mg.pb[t], rc = smu.mg.pc[t];
      for (int c = t * 32; c < t * 32 + 32; c++) {
        rb += P.wbg[c]; rc += P.wcg[c];
        if (c + 1 < NB) { P.Sb[c + 1] = rb; P.Sc[c + 1] = rc; }
      }
    }
    __syncthreads();
    const float SbT = P.Sb[NB];
    for (int qq = 0; qq < NB / 256; qq++) {
      int i = qq * 256 + t;
      float s1i = P.s1[i];
      int c = P.ci[i];
      float q1 = __expf(0.2f * s1i), q2 = __expf(s1i);
      float l = q1 * (SbT - P.Sb[c]) + q2 * P.Sc[c];
      P.f1[i] = q1 / l;
      P.f2[i] = q2 / l;
      atomicAdd(&smu.mg.histL[c], 1);
    }
    __syncthreads();
    {
      const int lo = t * 33;
      const int hi = min(lo + 33, NB + 1);
      int s = 0;
      for (int b = lo; b < hi; b++) s += smu.mg.histL[b];
      smu.mg.ps[t] = s;
      __syncthreads();
      if (t == 0) {
        int r = 0;
        for (int q = 0; q < 256; q++) { int v = smu.mg.ps[q]; smu.mg.ps[q] = r; r += v; }
      }
      __syncthreads();
      int r = smu.mg.ps[t];
      for (int b = lo; b < hi; b++) {
        P.istart[b] = r; P.cursor[b] = r; r += smu.mg.histL[b];
      }
      if (t == 255) P.istart[NB + 1] = r;
    }
  }
  grid.sync();

  // ---------------- C: pass1 chunk totals + fused scatter ----------------
  {
    const int cb = bid & 3;
    const int k  = bid >> 2;
    if (bid < 32) {
      const int i = bid * 256 + t;
      const int b = P.ci[i];
      const int pos = atomicAdd(&P.cursor[b], 1);
      P.ilist[pos] = i;
    }
    if (t < CH) {
      int g = k * CH + t;
      smu.pp.pj[t] = P.pi[g]; smu.pp.wb[t] = P.wbg[g]; smu.pp.wc[t] = P.wcg[g];
    }
    __syncthreads();
    const int n0 = cb * 1024 + t * 4;
    float b0 = 0.f, b1 = 0.f, b2 = 0.f, b3 = 0.f;
    float c0 = 0.f, c1 = 0.f, c2 = 0.f, c3 = 0.f;
#pragma unroll 8
    for (int c = 0; c < CH; c++) {
      uint2 hv = *(const uint2*)(P.h + (size_t)smu.pp.pj[c] * DF + n0);
      float h0 = bfu2f((uint16_t)hv.x), h1 = bfu2f((uint16_t)(hv.x >> 16));
      float h2 = bfu2f((uint16_t)hv.y), h3 = bfu2f((uint16_t)(hv.y >> 16));
      float vb = smu.pp.wb[c], vc = smu.pp.wc[c];
      b0 += vb * h0; b1 += vb * h1; b2 += vb * h2; b3 += vb * h3;
      c0 += vc * h0; c1 += vc * h1; c2 += vc * h2; c3 += vc * h3;
    }
    *(float4*)(P.Bct + (size_t)k * DF + n0) = make_float4(b0, b1, b2, b3);
    *(float4*)(P.Cct + (size_t)k * DF + n0) = make_float4(c0, c1, c2, c3);
  }
  grid.sync();

  // ---------------- D: per-column chunk-offset scan (64 blocks) ----------------
  if (bid < 64) {
    const int cl  = t & 63;
    const int seg = t >> 6;                    // 0..3 (32 chunks each)
    const int col = bid * 64 + cl;
    float sb = 0.f, sc = 0.f;
#pragma unroll 8
    for (int u = 0; u < NCH / 4; u++) {
      int kk = seg * (NCH / 4) + u;
      sb += P.Bct[(size_t)kk * DF + col];
      sc += P.Cct[(size_t)kk * DF + col];
    }
    smu.bo.sB[seg][cl] = sb; smu.bo.sC[seg][cl] = sc;
    __syncthreads();
    float rb = 0.f, rc = 0.f;
#pragma unroll
    for (int s = 0; s < 3; s++)
      if (s < seg) { rb += smu.bo.sB[s][cl]; rc += smu.bo.sC[s][cl]; }
#pragma unroll 4
    for (int u = 0; u < NCH / 4; u++) {
      int kk = seg * (NCH / 4) + u;
      P.Boff[(size_t)kk * DF + col] = rb;
      P.Coff[(size_t)kk * DF + col] = rc;
      rb += P.Bct[(size_t)kk * DF + col];
      rc += P.Cct[(size_t)kk * DF + col];
    }
    if (seg == 3) {
      P.Boff[(size_t)NCH * DF + col] = rb;      // = A_n
      P.Coff[(size_t)NCH * DF + col] = rc;
    }
  }
  grid.sync();

  // ---------------- E: pass2 sweep + direct emission ----------------
  {
    const int cb = bid & 3;
    const int k  = bid >> 2;
    if (t < CH) {
      int g = k * CH + t;
      smu.pp.pj[t] = P.pi[g]; smu.pp.wb[t] = P.wbg[g]; smu.pp.wc[t] = P.wcg[g];
    }
    if (t < CH + 2) smu.pp.se[t] = P.istart[k * CH + t];
    __syncthreads();
    const int n0 = cb * 1024 + t * 4;
    const float4 An = *(const float4*)(P.Boff + (size_t)NCH * DF + n0);
    const float4 Bo = *(const float4*)(P.Boff + (size_t)k * DF + n0);
    const float4 Co = *(const float4*)(P.Coff + (size_t)k * DF + n0);
    float b0 = Bo.x, b1 = Bo.y, b2 = Bo.z, b3 = Bo.w;
    float c0 = Co.x, c1 = Co.y, c2 = Co.z, c3 = Co.w;

    if (k == 0) {   // bucket 0: boundary before any j (c_i == 0)
      for (int idx = smu.pp.se[0]; idx < smu.pp.se[1]; idx++) {
        const int i = P.ilist[idx];
        const float fa = P.f1[i];
        *(float4*)(P.out + (size_t)i * DF + n0) =
            make_float4(fa * An.x, fa * An.y, fa * An.z, fa * An.w);
      }
    }
    for (int c = 0; c < CH; c++) {
      uint2 hv = *(const uint2*)(P.h + (size_t)smu.pp.pj[c] * DF + n0);
      float h0 = bfu2f((uint16_t)hv.x), h1 = bfu2f((uint16_t)(hv.x >> 16));
      float h2 = bfu2f((uint16_t)hv.y), h3 = bfu2f((uint16_t)(hv.y >> 16));
      float vb = smu.pp.wb[c], vc = smu.pp.wc[c];
      b0 += vb * h0; b1 += vb * h1; b2 += vb * h2; b3 += vb * h3;
      c0 += vc * h0; c1 += vc * h1; c2 += vc * h2; c3 += vc * h3;
      const int e0 = smu.pp.se[c + 1], e1 = smu.pp.se[c + 2];
      for (int idx = e0; idx < e1; idx++) {
        const int i = P.ilist[idx];
        const float fa = P.f1[i], fb = P.f2[i];
        *(float4*)(P.out + (size_t)i * DF + n0) = make_float4(
            fa * (An.x - b0) + fb * c0, fa * (An.y - b1) + fb * c1,
            fa * (An.z - b2) + fb * c2, fa * (An.w - b3) + fb * c3);
      }
    }
  }
}

// ---------------------------------------------------------------------------
extern "C" void kernel_launch(void* const* d_in, const int* in_sizes, int n_in,
                              void* d_out, int out_size, void* d_ws, size_t ws_size,
                              hipStream_t stream) {
  const float* x = (const float*)d_in[0];   // [8192][4096] fp32
  const float* W = (const float*)d_in[1];   // [4096][4096] fp32
  const float* a = (const float*)d_in[2];   // [8192] fp32
  float* out = (float*)d_out;               // [8192][4096] fp32

  char* ws = (char*)d_ws;
  uint16_t* h = (uint16_t*)ws;                 // 64 MB
  char* sm = ws + 67108864;
  float* s1       = (float*)(sm);
  float* s2       = (float*)(sm + 65536);
  float* s2sorted = (float*)(sm + 131072);
  int*   pi       = (int*)  (sm + 196608);
  int*   ci       = (int*)  (sm + 262144);
  float* Sb       = (float*)(sm + 327680);     // NB+1 floats
  float* Sc       = (float*)(sm + 393216);
  float* wbg      = (float*)(sm + 458752);
  float* wcg      = (float*)(sm + 524288);
  float* f1       = (float*)(sm + 589824);
  float* f2       = (float*)(sm + 655360);
  int*   istart   = (int*)  (sm + 786432);     // NB+2 ints
  int*   cursor   = (int*)  (sm + 851968);     // NB+1 ints
  int*   ilist    = (int*)  (sm + 917504);     // NB ints
  float* Bct      = (float*)(sm + 1048576);    // 2 MB (= s1p[64][8192] first)
  float* Cct      = (float*)(sm + 3145728);    // 2 MB (= s2p[64][8192] first)
  float* Boff     = (float*)(sm + 5242880);    // (NCH+1)*DF*4 ~ 2.02 MB
  float* Coff     = (float*)(sm + 7602176);    // ~2.02 MB (ends sm+9.96MB)
  char* base2 = ws + 67108864 + 10485760;      // staging (dead after gemm)
  uint16_t* xb = (uint16_t*)base2;             // 64 MB
  uint16_t* Wb = (uint16_t*)(base2 + 67108864);// 32 MB  (total ws ~169 MB)
  float* s1p = Bct;   // alias: partials dead before Bct is written
  float* s2p = Cct;

  // 1: cvt x and W
  cvt_all<<<1024, 256, 0, stream>>>(x, xb, W, Wb);

  // 2: GEMM + s12 panel partials
  gemm_nt_async<<<(NB / 256) * (DF / 256), 512, 0, stream>>>(
      xb, Wb, h, a, s1p, s2p);

  // 3: everything else in one cooperative kernel
  PostArgs P;
  P.h = h; P.s1p = s1p; P.s2p = s2p; P.s1 = s1; P.s2 = s2;
  P.pi = pi; P.s2sorted = s2sorted; P.ci = ci;
  P.Sb = Sb; P.Sc = Sc; P.wbg = wbg; P.wcg = wcg;
  P.f1 = f1; P.f2 = f2;
  P.istart = istart; P.cursor = cursor; P.ilist = ilist;
  P.Bct = Bct; P.Cct = Cct; P.Boff = Boff; P.Coff = Coff;
  P.out = out;
  void* kargs[] = { &P };
  hipLaunchCooperativeKernel((const void*)gat_post, dim3(512), dim3(256),
                             kargs, 0, stream);
}

// Round 5
// 771.831 us; speedup vs baseline: 1.3118x; 1.3118x over previous
//
#include <hip/hip_runtime.h>
#include <hip/hip_bf16.h>
#include <stdint.h>

// ---------------------------------------------------------------------------
// GraphAttentionLayer: out = softmax(lrelu(s1_i + s2_j)) @ h,  h = x @ W^T
// Round 8: coop reverted (grid.sync cost >> launch cost; measured 505us for
// ~180us of content). Plain stream kernels, 6 launches:
//   cvt_all | gemm(+s12 partials) | rankcount(self-reduce s2 from partials,
//   emits wbg/wcg at sorted pos, +p bank stagger) | megapass1(block0 = scan+
//   finalize+bucketscan+scatter, blocks 1..512 = pass1 — independent, no sync)
//   | boff | pass2
// ---------------------------------------------------------------------------

typedef float  f32x4  __attribute__((ext_vector_type(4)));
typedef __bf16 bf16x8 __attribute__((ext_vector_type(8)));

#define AS1 __attribute__((address_space(1)))
#define AS3 __attribute__((address_space(3)))

constexpr int NB  = 8192;    // batch rows (i and j)
constexpr int DF  = 4096;    // feature dim
constexpr int CH  = 64;      // sweep chunk length
constexpr int NCH = NB / CH; // 128

constexpr int GK  = DF;      // GEMM K
constexpr int BKK = 64;      // GEMM K-tile
constexpr int NT2 = GK / BKK;

__device__ __forceinline__ uint16_t f2bf_u(float f) {   // RNE fp32 -> bf16
  union { float f; uint32_t u; } x; x.f = f;
  return (uint16_t)((x.u + 0x7FFFu + ((x.u >> 16) & 1u)) >> 16);
}
__device__ __forceinline__ float bfu2f(uint16_t v) {
  union { uint32_t u; float f; } x; x.u = ((uint32_t)v) << 16;
  return x.f;
}

// --------------------------- fp32 -> bf16 convert (x and W in one) ----------
__global__ __launch_bounds__(256) void cvt_all(
    const float* __restrict__ x, uint16_t* __restrict__ xb,
    const float* __restrict__ W, uint16_t* __restrict__ Wb) {
  const int idx = blockIdx.x * 256 + threadIdx.x;
  const int stride = gridDim.x * 256;
  const int n4x = (NB * DF) / 4, n4w = (DF * DF) / 4;
  for (int i = idx; i < n4x; i += stride) {
    float4 v = ((const float4*)x)[i];
    ushort4 o;
    o.x = f2bf_u(v.x); o.y = f2bf_u(v.y); o.z = f2bf_u(v.z); o.w = f2bf_u(v.w);
    ((ushort4*)xb)[i] = o;
  }
  for (int i = idx; i < n4w; i += stride) {
    float4 v = ((const float4*)W)[i];
    ushort4 o;
    o.x = f2bf_u(v.x); o.y = f2bf_u(v.y); o.z = f2bf_u(v.z); o.w = f2bf_u(v.w);
    ((ushort4*)Wb)[i] = o;
  }
}

// --------------------------- NT bf16 GEMM: async dbuf + s12 partials --------
// C[M=8192][N=4096] = A[8192][4096] * B[4096][4096]^T, bf16 in/out, fp32 acc.
// Epilogue: per-panel-quarter partial dots s1p/s2p[q=bx*4+wn][row] (plain
// stores, no atomics — R3 showed atomics cost +48us via L2 line contention).

#define STAGE_A(tt, half) do {                                                 \
  const uint16_t* g0_ = Ag + (size_t)((half) * 128) * GK + (size_t)(tt) * BKK; \
  uint32_t d_ = ((uint32_t)((tt) & 1)) * 32768u + (uint32_t)(half) * 8192u +   \
                (uint32_t)wave * 512u;                                         \
  __builtin_amdgcn_global_load_lds((const AS1 void*)g0_,                       \
      (AS3 void*)(lds + d_), 16, 0, 0);                                        \
  __builtin_amdgcn_global_load_lds((const AS1 void*)(g0_ + (size_t)64 * GK),   \
      (AS3 void*)(lds + d_ + 4096u), 16, 0, 0);                                \
} while (0)

#define STAGE_B(tt, half) do {                                                 \
  const uint16_t* g0_ = Bg + (size_t)((half) * 128) * GK + (size_t)(tt) * BKK; \
  uint32_t d_ = ((uint32_t)((tt) & 1)) * 32768u + 16384u +                     \
                (uint32_t)(half) * 8192u + (uint32_t)wave * 512u;              \
  __builtin_amdgcn_global_load_lds((const AS1 void*)g0_,                       \
      (AS3 void*)(lds + d_), 16, 0, 0);                                        \
  __builtin_amdgcn_global_load_lds((const AS1 void*)(g0_ + (size_t)64 * GK),   \
      (AS3 void*)(lds + d_ + 4096u), 16, 0, 0);                                \
} while (0)

#define LDA(mh) do {                                                           \
  _Pragma("unroll") for (int mf = 0; mf < 4; ++mf)                             \
    _Pragma("unroll") for (int ks = 0; ks < 2; ++ks)                           \
      aF[mf][ks] = *(const bf16x8*)(lds + bufo +                               \
          (uint32_t)(wm * 128 + (mh) * 64 + mf * 16 + lr) * 64u +              \
          (uint32_t)((ks * 32 + lg * 8) ^ swl));                               \
} while (0)

#define LDB(nh) do {                                                           \
  _Pragma("unroll") for (int nf = 0; nf < 2; ++nf)                             \
    _Pragma("unroll") for (int ks = 0; ks < 2; ++ks)                           \
      bF[nf][ks] = *(const bf16x8*)(lds + bufo + 16384u +                      \
          (uint32_t)(wn * 64 + (nh) * 32 + nf * 16 + lr) * 64u +               \
          (uint32_t)((ks * 32 + lg * 8) ^ swl));                               \
} while (0)

#define MMA(mh, nh) do {                                                       \
  _Pragma("unroll") for (int ks = 0; ks < 2; ++ks)                             \
    _Pragma("unroll") for (int mf = 0; mf < 4; ++mf)                           \
      _Pragma("unroll") for (int nf = 0; nf < 2; ++nf)                         \
        acc[(mh) * 4 + mf][(nh) * 2 + nf] =                                    \
            __builtin_amdgcn_mfma_f32_16x16x32_bf16(aF[mf][ks], bF[nf][ks],    \
                acc[(mh) * 4 + mf][(nh) * 2 + nf], 0, 0, 0);                   \
} while (0)

__global__ __launch_bounds__(512, 2) void gemm_nt_async(
    const uint16_t* __restrict__ A, const uint16_t* __restrict__ B,
    uint16_t* __restrict__ C, const float* __restrict__ a,
    float* __restrict__ s1p, float* __restrict__ s2p) {
  __shared__ uint16_t lds[65536];   // 128 KiB: [buf][A|B][256*64]

  const int tid  = threadIdx.x;
  const int wave = tid >> 6;
  const int lane = tid & 63;
  const int lr   = lane & 15;
  const int lg   = lane >> 4;        // 0..3
  const int wm   = wave >> 2;        // 0..1  (M half)
  const int wn   = wave & 3;         // 0..3  (N quarter)
  const int swl  = (lr & 7) << 3;    // read-side XOR swizzle (elements)

  // XCD-aware bijective swizzle over 512 blocks (512 % 8 == 0)
  const int bid = blockIdx.x;
  const int swz = (bid & 7) * 64 + (bid >> 3);
  const int bx  = swz & 15;          // N tile (16)
  const int by  = swz >> 4;          // M tile (32)
  const int rowBase = by * 256;
  const int colBase = bx * 256;

  // stage source: thread t covers LDS row sr, 16-B chunk (t&7); source chunk
  // is pre-swizzled so that linear LDS dest + swizzled read = identity.
  const int sr  = tid >> 3;                    // 0..63
  const int sch = (tid & 7) ^ (sr & 7);
  const uint16_t* Ag = A + (size_t)(rowBase + sr) * GK + sch * 8;
  const uint16_t* Bg = B + (size_t)(colBase + sr) * GK + sch * 8;

  f32x4 acc[8][4];
#pragma unroll
  for (int mf = 0; mf < 8; ++mf)
#pragma unroll
    for (int nf = 0; nf < 4; ++nf) acc[mf][nf] = (f32x4){0.f, 0.f, 0.f, 0.f};

  // prologue: stage tile 0 -> buf0, wait, sync
  STAGE_A(0, 0);
  STAGE_A(0, 1);
  STAGE_B(0, 0);
  STAGE_B(0, 1);
  asm volatile("s_waitcnt vmcnt(0)" ::: "memory");
  __builtin_amdgcn_s_barrier();

  bf16x8 aF[4][2], bF[2][2];

  for (int t = 0; t < NT2; ++t) {
    const uint32_t bufo = ((uint32_t)(t & 1)) * 32768u;

    // prefetch next tile -> OTHER buffer (never touches buffer being read)
    if (t + 1 < NT2) {
      STAGE_A(t + 1, 0);
      STAGE_A(t + 1, 1);
      STAGE_B(t + 1, 0);
      STAGE_B(t + 1, 1);
    }

    LDA(0); LDB(0);
    MMA(0, 0);
    LDB(1);
    MMA(0, 1);
    LDA(1);
    MMA(1, 1);
    LDB(0);          // re-read B-half0 (cheaper than +16 live VGPRs)
    MMA(1, 0);

    if (t + 1 < NT2) {
      asm volatile("s_waitcnt vmcnt(0)" ::: "memory");
      __builtin_amdgcn_s_barrier();
    }
  }

  // epilogue: C/D layout col = lane&15, row = (lane>>4)*4 + reg
  const int r0 = rowBase + wm * 128 + lg * 4;
  const int c0 = colBase + wn * 64 + lr;
#pragma unroll
  for (int mf = 0; mf < 8; ++mf)
#pragma unroll
    for (int nf = 0; nf < 4; ++nf)
#pragma unroll
      for (int e = 0; e < 4; ++e)
        C[(size_t)(r0 + mf * 16 + e) * (size_t)DF + (c0 + nf * 16)] =
            f2bf_u(acc[mf][nf][e]);

  // ---- s12 partials: quarter q = bx*4 + wn covers cols [q*64, q*64+64) ----
  float a1v[4], a2v[4];
#pragma unroll
  for (int nf = 0; nf < 4; ++nf) {
    int col = c0 + nf * 16;
    a1v[nf] = a[col];
    a2v[nf] = a[DF + col];
  }
  const int q = bx * 4 + wn;
#pragma unroll
  for (int mf = 0; mf < 8; ++mf) {
#pragma unroll
    for (int e = 0; e < 4; ++e) {
      float p1 = 0.f, p2 = 0.f;
#pragma unroll
      for (int nf = 0; nf < 4; ++nf) {
        float hv = acc[mf][nf][e];
        p1 += hv * a1v[nf];
        p2 += hv * a2v[nf];
      }
      p1 += __shfl_xor(p1, 1, 64); p1 += __shfl_xor(p1, 2, 64);
      p1 += __shfl_xor(p1, 4, 64); p1 += __shfl_xor(p1, 8, 64);
      p2 += __shfl_xor(p2, 1, 64); p2 += __shfl_xor(p2, 2, 64);
      p2 += __shfl_xor(p2, 4, 64); p2 += __shfl_xor(p2, 8, 64);
      if (lr == 0) {
        int row = r0 + mf * 16 + e;
        s1p[(size_t)q * NB + row] = p1;
        s2p[(size_t)q * NB + row] = p2;
      }
    }
  }
}

// --------------------------- rank + count (self-reducing) -------------------
// 128 blocks x 256 threads. Each block:
//  - reduces full s2[8192] from s2p[64][8192] into LDS (register-accumulated,
//    coalesced; s2p is 2 MB -> L2/L3-hot)
//  - reduces s1 for its own 64 i's from s1p
//  - 4-part j-scan with +p rotation (parts hit banks {0,4,8,12}: conflict-free)
//  - emits pi, s2sorted, ci, s1, and wbg/wcg = exp(.) at the sorted position
__global__ __launch_bounds__(256) void rankcount_kernel(
    const float* __restrict__ s1p, const float* __restrict__ s2p,
    float* __restrict__ s1, int* __restrict__ pi,
    float* __restrict__ s2sorted, int* __restrict__ ci,
    float* __restrict__ wbg, float* __restrict__ wcg) {
  __shared__ float ld[NB];
  const int t   = threadIdx.x;
  const int bid = blockIdx.x;

  // self-reduce s2: thread t owns rows {t + 256j}, deterministic q-ascending
  float accr[32];
#pragma unroll
  for (int j = 0; j < 32; j++) accr[j] = 0.f;
  for (int q = 0; q < 64; q++) {
    const float* plane = s2p + (size_t)q * NB;
#pragma unroll
    for (int j = 0; j < 32; j++) accr[j] += plane[t + 256 * j];
  }
#pragma unroll
  for (int j = 0; j < 32; j++) ld[t + 256 * j] = accr[j];

  // s1 for this block's i's: i = bid*64 + (t>>2); 4 parts over q, shfl-combine
  const int i = bid * 64 + (t >> 2);
  const int p = t & 3;
  float s1v = 0.f;
  for (int q = p * 16; q < p * 16 + 16; q++) s1v += s1p[(size_t)q * NB + i];
  s1v += __shfl_xor(s1v, 1, 64);
  s1v += __shfl_xor(s1v, 2, 64);
  __syncthreads();

  const float v   = ld[i];
  const float thr = -s1v;
  int cr = 0, cc = 0;
  const int q0 = p * (NB / 16);          // 512 float4 per part
  for (int it = 0; it < NB / 16; it++) {
    int qq = q0 + ((it + p) & (NB / 16 - 1));   // +p stagger: distinct banks
    float4 u = ((const float4*)ld)[qq];
    int jj = qq * 4;
    cr += (u.x > v) || (u.x == v && (jj + 0) < i);
    cr += (u.y > v) || (u.y == v && (jj + 1) < i);
    cr += (u.z > v) || (u.z == v && (jj + 2) < i);
    cr += (u.w > v) || (u.w == v && (jj + 3) < i);
    cc += (u.x > thr) + (u.y > thr) + (u.z > thr) + (u.w > thr);
  }
  cr += __shfl_xor(cr, 1, 64); cr += __shfl_xor(cr, 2, 64);
  cc += __shfl_xor(cc, 1, 64); cc += __shfl_xor(cc, 2, 64);
  if (p == 0) {
    pi[cr] = i;
    s2sorted[cr] = v;
    ci[i] = cc;
    s1[i] = s1v;
    wbg[cr] = __expf(0.2f * v);
    wcg[cr] = __expf(v);
  }
}

// --------------------------- megapass1 --------------------------------------
// block 0  : Sb/Sc prefix scan + finalize (f1,f2) + bucket scan (istart) +
//            scatter (ilist) — all from rankcount outputs.
// blocks 1..512 : pass1 chunk totals (independent of block 0; no sync needed).
union MpSmem {
  struct { float pb[256]; float pc[256]; int histL[NB + 1]; int ps[256]; } mg;
  struct { int pj[CH]; float wb[CH]; float wc[CH]; } pp;
};

__global__ __launch_bounds__(256) void megapass1_kernel(
    const uint16_t* __restrict__ h, const int* __restrict__ pi,
    const float* __restrict__ wbg, const float* __restrict__ wcg,
    const float* __restrict__ s1, const int* __restrict__ ci,
    float* __restrict__ Sb, float* __restrict__ Sc,
    float* __restrict__ f1, float* __restrict__ f2,
    int* __restrict__ istart, int* __restrict__ ilist,
    float* __restrict__ Bct, float* __restrict__ Cct) {
  __shared__ MpSmem smu;
  const int t   = threadIdx.x;
  const int bid = blockIdx.x;

  if (bid == 0) {
    // ---- scan: prefix sums of wbg/wcg (already exp'd by rankcount) ----
    for (int g = t; g <= NB; g += 256) smu.mg.histL[g] = 0;
    float sb = 0.f, sc = 0.f;
    for (int c = t * 32; c < t * 32 + 32; c++) { sb += wbg[c]; sc += wcg[c]; }
    smu.mg.pb[t] = sb; smu.mg.pc[t] = sc;
    __syncthreads();
    if (t == 0) {
      float rb = 0.f, rc = 0.f;
      for (int q = 0; q < 256; q++) {
        float tb = smu.mg.pb[q], tc = smu.mg.pc[q];
        smu.mg.pb[q] = rb; smu.mg.pc[q] = rc;
        rb += tb; rc += tc;
      }
      Sb[0] = 0.f; Sc[0] = 0.f;
      Sb[NB] = rb; Sc[NB] = rc;
    }
    __syncthreads();
    {
      float rb = smu.mg.pb[t], rc = smu.mg.pc[t];
      for (int c = t * 32; c < t * 32 + 32; c++) {
        rb += wbg[c]; rc += wcg[c];
        if (c + 1 < NB) { Sb[c + 1] = rb; Sc[c + 1] = rc; }
      }
    }
    __syncthreads();
    // ---- finalize: per-i scalars + LDS histogram ----
    const float SbT = Sb[NB];
    for (int qq = 0; qq < NB / 256; qq++) {
      int i = qq * 256 + t;
      float s1i = s1[i];
      int c = ci[i];
      float q1 = __expf(0.2f * s1i), q2 = __expf(s1i);
      float l = q1 * (SbT - Sb[c]) + q2 * Sc[c];
      f1[i] = q1 / l;
      f2[i] = q2 / l;
      atomicAdd(&smu.mg.histL[c], 1);
    }
    __syncthreads();
    // ---- bucket scan -> istart; histL becomes the cursor ----
    {
      const int lo = t * 33;
      const int hi = min(lo + 33, NB + 1);
      int s = 0;
      for (int b = lo; b < hi; b++) s += smu.mg.histL[b];
      smu.mg.ps[t] = s;
      __syncthreads();
      if (t == 0) {
        int r = 0;
        for (int q = 0; q < 256; q++) {
          int v = smu.mg.ps[q]; smu.mg.ps[q] = r; r += v;
        }
      }
      __syncthreads();
      int r = smu.mg.ps[t];
      for (int b = lo; b < hi; b++) {
        istart[b] = r;
        int hv = smu.mg.histL[b];
        smu.mg.histL[b] = r;          // cursor
        r += hv;
      }
      if (t == 255) istart[NB + 1] = r;
    }
    __syncthreads();
    // ---- scatter: ilist via LDS cursor ----
    for (int qq = 0; qq < NB / 256; qq++) {
      int i = qq * 256 + t;
      int pos = atomicAdd(&smu.mg.histL[ci[i]], 1);
      ilist[pos] = i;
    }
    return;
  }

  // ---- pass1: chunk totals (blocks 1..512) ----
  const int fb = bid - 1;
  const int cb = fb & 3;
  const int k  = fb >> 2;
  if (t < CH) {
    int g = k * CH + t;
    smu.pp.pj[t] = pi[g]; smu.pp.wb[t] = wbg[g]; smu.pp.wc[t] = wcg[g];
  }
  __syncthreads();
  const int n0 = cb * 1024 + t * 4;
  float b0 = 0.f, b1 = 0.f, b2 = 0.f, b3 = 0.f;
  float c0 = 0.f, c1 = 0.f, c2 = 0.f, c3 = 0.f;
#pragma unroll 8
  for (int c = 0; c < CH; c++) {
    uint2 hv = *(const uint2*)(h + (size_t)smu.pp.pj[c] * DF + n0);
    float h0 = bfu2f((uint16_t)hv.x), h1 = bfu2f((uint16_t)(hv.x >> 16));
    float h2 = bfu2f((uint16_t)hv.y), h3 = bfu2f((uint16_t)(hv.y >> 16));
    float vb = smu.pp.wb[c], vc = smu.pp.wc[c];
    b0 += vb * h0; b1 += vb * h1; b2 += vb * h2; b3 += vb * h3;
    c0 += vc * h0; c1 += vc * h1; c2 += vc * h2; c3 += vc * h3;
  }
  *(float4*)(Bct + (size_t)k * DF + n0) = make_float4(b0, b1, b2, b3);
  *(float4*)(Cct + (size_t)k * DF + n0) = make_float4(c0, c1, c2, c3);
}

// --------------------------- chunk offset scan (per column) -----------------
__global__ __launch_bounds__(256) void boff_kernel(
    const float* __restrict__ Bct, const float* __restrict__ Cct,
    float* __restrict__ Boff, float* __restrict__ Coff) {
  __shared__ float sB[4][64], sC[4][64];
  const int t   = threadIdx.x;
  const int cl  = t & 63;
  const int seg = t >> 6;                    // 0..3 (32 chunks each)
  const int col = blockIdx.x * 64 + cl;
  float sb = 0.f, sc = 0.f;
#pragma unroll 8
  for (int u = 0; u < NCH / 4; u++) {
    int kk = seg * (NCH / 4) + u;
    sb += Bct[(size_t)kk * DF + col];
    sc += Cct[(size_t)kk * DF + col];
  }
  sB[seg][cl] = sb; sC[seg][cl] = sc;
  __syncthreads();
  float rb = 0.f, rc = 0.f;
#pragma unroll
  for (int s = 0; s < 3; s++)
    if (s < seg) { rb += sB[s][cl]; rc += sC[s][cl]; }
#pragma unroll 4
  for (int u = 0; u < NCH / 4; u++) {
    int kk = seg * (NCH / 4) + u;
    Boff[(size_t)kk * DF + col] = rb;
    Coff[(size_t)kk * DF + col] = rc;
    rb += Bct[(size_t)kk * DF + col];
    rc += Cct[(size_t)kk * DF + col];
  }
  if (seg == 3) {
    Boff[(size_t)NCH * DF + col] = rb;      // = A_n
    Coff[(size_t)NCH * DF + col] = rc;
  }
}

// --------------------------- pass2: sweep + direct emission -----------------
__global__ __launch_bounds__(256) void pass2_kernel(
    const uint16_t* __restrict__ h, const int* __restrict__ pi,
    const float* __restrict__ wbg, const float* __restrict__ wcg,
    const float* __restrict__ Boff, const float* __restrict__ Coff,
    const int* __restrict__ istart, const int* __restrict__ ilist,
    const float* __restrict__ f1, const float* __restrict__ f2,
    float* __restrict__ out) {
  __shared__ int   pj[CH];
  __shared__ float wb[CH], wc[CH];
  __shared__ int   se[CH + 2];
  const int t  = threadIdx.x;
  const int cb = blockIdx.x;
  const int k  = blockIdx.y;
  if (t < CH) {
    int g = k * CH + t;
    pj[t] = pi[g]; wb[t] = wbg[g]; wc[t] = wcg[g];
  }
  if (t < CH + 2) se[t] = istart[k * CH + t];
  __syncthreads();
  const int n0 = cb * 1024 + t * 4;
  const float4 An = *(const float4*)(Boff + (size_t)NCH * DF + n0);
  const float4 Bo = *(const float4*)(Boff + (size_t)k * DF + n0);
  const float4 Co = *(const float4*)(Coff + (size_t)k * DF + n0);
  float b0 = Bo.x, b1 = Bo.y, b2 = Bo.z, b3 = Bo.w;
  float c0 = Co.x, c1 = Co.y, c2 = Co.z, c3 = Co.w;

  if (k == 0) {   // bucket 0: boundary before any j (c_i == 0)
    for (int idx = se[0]; idx < se[1]; idx++) {
      const int i = ilist[idx];
      const float fa = f1[i];
      *(float4*)(out + (size_t)i * DF + n0) =
          make_float4(fa * An.x, fa * An.y, fa * An.z, fa * An.w);
    }
  }
  for (int c = 0; c < CH; c++) {
    uint2 hv = *(const uint2*)(h + (size_t)pj[c] * DF + n0);
    float h0 = bfu2f((uint16_t)hv.x), h1 = bfu2f((uint16_t)(hv.x >> 16));
    float h2 = bfu2f((uint16_t)hv.y), h3 = bfu2f((uint16_t)(hv.y >> 16));
    float vb = wb[c], vc = wc[c];
    b0 += vb * h0; b1 += vb * h1; b2 += vb * h2; b3 += vb * h3;
    c0 += vc * h0; c1 += vc * h1; c2 += vc * h2; c3 += vc * h3;
    const int e0 = se[c + 1], e1 = se[c + 2];
    for (int idx = e0; idx < e1; idx++) {
      const int i = ilist[idx];
      const float fa = f1[i], fb = f2[i];
      *(float4*)(out + (size_t)i * DF + n0) = make_float4(
          fa * (An.x - b0) + fb * c0, fa * (An.y - b1) + fb * c1,
          fa * (An.z - b2) + fb * c2, fa * (An.w - b3) + fb * c3);
    }
  }
}

// ---------------------------------------------------------------------------
extern "C" void kernel_launch(void* const* d_in, const int* in_sizes, int n_in,
                              void* d_out, int out_size, void* d_ws, size_t ws_size,
                              hipStream_t stream) {
  const float* x = (const float*)d_in[0];   // [8192][4096] fp32
  const float* W = (const float*)d_in[1];   // [4096][4096] fp32
  const float* a = (const float*)d_in[2];   // [8192] fp32
  float* out = (float*)d_out;               // [8192][4096] fp32

  char* ws = (char*)d_ws;
  uint16_t* h = (uint16_t*)ws;                 // 64 MB
  char* sm = ws + 67108864;
  float* s1       = (float*)(sm);
  float* s2sorted = (float*)(sm + 131072);
  int*   pi       = (int*)  (sm + 196608);
  int*   ci       = (int*)  (sm + 262144);
  float* Sb       = (float*)(sm + 327680);     // NB+1 floats
  float* Sc       = (float*)(sm + 393216);
  float* wbg      = (float*)(sm + 458752);
  float* wcg      = (float*)(sm + 524288);
  float* f1       = (float*)(sm + 589824);
  float* f2       = (float*)(sm + 655360);
  int*   istart   = (int*)  (sm + 786432);     // NB+2 ints
  int*   ilist    = (int*)  (sm + 917504);     // NB ints
  float* Bct      = (float*)(sm + 1048576);    // 2 MB (= s1p[64][8192] first)
  float* Cct      = (float*)(sm + 3145728);    // 2 MB (= s2p[64][8192] first)
  float* Boff     = (float*)(sm + 5242880);    // (NCH+1)*DF*4 ~ 2.02 MB
  float* Coff     = (float*)(sm + 7602176);    // ~2.02 MB (ends sm+9.96MB)
  char* base2 = ws + 67108864 + 10485760;      // staging (dead after gemm)
  uint16_t* xb = (uint16_t*)base2;             // 64 MB
  uint16_t* Wb = (uint16_t*)(base2 + 67108864);// 32 MB  (total ws ~169 MB)
  float* s1p = Bct;   // alias: partials dead before Bct is written
  float* s2p = Cct;

  // 1: cvt x and W
  cvt_all<<<1024, 256, 0, stream>>>(x, xb, W, Wb);

  // 2: GEMM + s12 panel partials
  gemm_nt_async<<<(NB / 256) * (DF / 256), 512, 0, stream>>>(
      xb, Wb, h, a, s1p, s2p);

  // 3: rank + count (self-reducing, emits wbg/wcg/s1)
  rankcount_kernel<<<NB / 64, 256, 0, stream>>>(
      s1p, s2p, s1, pi, s2sorted, ci, wbg, wcg);

  // 4: block0 = scan+finalize+bucketscan+scatter; blocks 1..512 = pass1
  megapass1_kernel<<<1 + (DF / 1024) * NCH, 256, 0, stream>>>(
      h, pi, wbg, wcg, s1, ci, Sb, Sc, f1, f2, istart, ilist, Bct, Cct);

  // 5: per-column chunk-offset scan
  boff_kernel<<<DF / 64, 256, 0, stream>>>(Bct, Cct, Boff, Coff);

  // 6: sweep + direct emission
  pass2_kernel<<<dim3(DF / 1024, NCH), 256, 0, stream>>>(
      h, pi, wbg, wcg, Boff, Coff, istart, ilist, f1, f2, out);
}

// Round 6
// 747.609 us; speedup vs baseline: 1.3543x; 1.0324x over previous
//
#include <hip/hip_runtime.h>
#include <hip/hip_bf16.h>
#include <stdint.h>

// ---------------------------------------------------------------------------
// GraphAttentionLayer: out = softmax(lrelu(s1_i + s2_j)) @ h,  h = x @ W^T
// Round 9: revert R5's rankcount self-reduce (256 MB cross-XCD dirty re-reads,
// ~120-170us). s1/s2 now finished inside the GEMM: per-wave quarter partials
// -> LDS (buf0 area, dead on the last odd K-tile) -> cross-wave reduce -> ONE
// atomicAdd per row per block (262K atomics, 4x fewer than R3's +48us variant).
// rankcount reads prereduced s1/s2 (64 KB). 6 launches:
//   cvt_all(+zero s1/s2) | gemm(+s12 LDS-reduced atomics) | rankcount |
//   megapass1 | boff | pass2
// ---------------------------------------------------------------------------

typedef float  f32x4  __attribute__((ext_vector_type(4)));
typedef __bf16 bf16x8 __attribute__((ext_vector_type(8)));

#define AS1 __attribute__((address_space(1)))
#define AS3 __attribute__((address_space(3)))

constexpr int NB  = 8192;    // batch rows (i and j)
constexpr int DF  = 4096;    // feature dim
constexpr int CH  = 64;      // sweep chunk length
constexpr int NCH = NB / CH; // 128

constexpr int GK  = DF;      // GEMM K
constexpr int BKK = 64;      // GEMM K-tile
constexpr int NT2 = GK / BKK;

__device__ __forceinline__ uint16_t f2bf_u(float f) {   // RNE fp32 -> bf16
  union { float f; uint32_t u; } x; x.f = f;
  return (uint16_t)((x.u + 0x7FFFu + ((x.u >> 16) & 1u)) >> 16);
}
__device__ __forceinline__ float bfu2f(uint16_t v) {
  union { uint32_t u; float f; } x; x.u = ((uint32_t)v) << 16;
  return x.f;
}

// --------------------------- fp32 -> bf16 convert (x and W in one) ----------
__global__ __launch_bounds__(256) void cvt_all(
    const float* __restrict__ x, uint16_t* __restrict__ xb,
    const float* __restrict__ W, uint16_t* __restrict__ Wb,
    float* __restrict__ z1, float* __restrict__ z2) {
  const int idx = blockIdx.x * 256 + threadIdx.x;
  const int stride = gridDim.x * 256;
  const int n4x = (NB * DF) / 4, n4w = (DF * DF) / 4;
  if (idx < NB) { z1[idx] = 0.f; z2[idx] = 0.f; }   // gemm atomic targets
  for (int i = idx; i < n4x; i += stride) {
    float4 v = ((const float4*)x)[i];
    ushort4 o;
    o.x = f2bf_u(v.x); o.y = f2bf_u(v.y); o.z = f2bf_u(v.z); o.w = f2bf_u(v.w);
    ((ushort4*)xb)[i] = o;
  }
  for (int i = idx; i < n4w; i += stride) {
    float4 v = ((const float4*)W)[i];
    ushort4 o;
    o.x = f2bf_u(v.x); o.y = f2bf_u(v.y); o.z = f2bf_u(v.z); o.w = f2bf_u(v.w);
    ((ushort4*)Wb)[i] = o;
  }
}

// --------------------------- NT bf16 GEMM: async dbuf + s12 epilogue --------
// C[M=8192][N=4096] = A[8192][4096] * B[4096][4096]^T, bf16 in/out, fp32 acc.
// Epilogue: s1/s2 row dots vs a1/a2: shfl over lr -> LDS stash per wave ->
// cross-wave reduce -> one atomicAdd per row per block.

#define STAGE_A(tt, half) do {                                                 \
  const uint16_t* g0_ = Ag + (size_t)((half) * 128) * GK + (size_t)(tt) * BKK; \
  uint32_t d_ = ((uint32_t)((tt) & 1)) * 32768u + (uint32_t)(half) * 8192u +   \
                (uint32_t)wave * 512u;                                         \
  __builtin_amdgcn_global_load_lds((const AS1 void*)g0_,                       \
      (AS3 void*)(lds + d_), 16, 0, 0);                                        \
  __builtin_amdgcn_global_load_lds((const AS1 void*)(g0_ + (size_t)64 * GK),   \
      (AS3 void*)(lds + d_ + 4096u), 16, 0, 0);                                \
} while (0)

#define STAGE_B(tt, half) do {                                                 \
  const uint16_t* g0_ = Bg + (size_t)((half) * 128) * GK + (size_t)(tt) * BKK; \
  uint32_t d_ = ((uint32_t)((tt) & 1)) * 32768u + 16384u +                     \
                (uint32_t)(half) * 8192u + (uint32_t)wave * 512u;              \
  __builtin_amdgcn_global_load_lds((const AS1 void*)g0_,                       \
      (AS3 void*)(lds + d_), 16, 0, 0);                                        \
  __builtin_amdgcn_global_load_lds((const AS1 void*)(g0_ + (size_t)64 * GK),   \
      (AS3 void*)(lds + d_ + 4096u), 16, 0, 0);                                \
} while (0)

#define LDA(mh) do {                                                           \
  _Pragma("unroll") for (int mf = 0; mf < 4; ++mf)                             \
    _Pragma("unroll") for (int ks = 0; ks < 2; ++ks)                           \
      aF[mf][ks] = *(const bf16x8*)(lds + bufo +                               \
          (uint32_t)(wm * 128 + (mh) * 64 + mf * 16 + lr) * 64u +              \
          (uint32_t)((ks * 32 + lg * 8) ^ swl));                               \
} while (0)

#define LDB(nh) do {                                                           \
  _Pragma("unroll") for (int nf = 0; nf < 2; ++nf)                             \
    _Pragma("unroll") for (int ks = 0; ks < 2; ++ks)                           \
      bF[nf][ks] = *(const bf16x8*)(lds + bufo + 16384u +                      \
          (uint32_t)(wn * 64 + (nh) * 32 + nf * 16 + lr) * 64u +               \
          (uint32_t)((ks * 32 + lg * 8) ^ swl));                               \
} while (0)

#define MMA(mh, nh) do {                                                       \
  _Pragma("unroll") for (int ks = 0; ks < 2; ++ks)                             \
    _Pragma("unroll") for (int mf = 0; mf < 4; ++mf)                           \
      _Pragma("unroll") for (int nf = 0; nf < 2; ++nf)                         \
        acc[(mh) * 4 + mf][(nh) * 2 + nf] =                                    \
            __builtin_amdgcn_mfma_f32_16x16x32_bf16(aF[mf][ks], bF[nf][ks],    \
                acc[(mh) * 4 + mf][(nh) * 2 + nf], 0, 0, 0);                   \
} while (0)

__global__ __launch_bounds__(512, 2) void gemm_nt_async(
    const uint16_t* __restrict__ A, const uint16_t* __restrict__ B,
    uint16_t* __restrict__ C, const float* __restrict__ a,
    float* __restrict__ s1g, float* __restrict__ s2g) {
  __shared__ uint16_t lds[65536];   // 128 KiB: [buf][A|B][256*64]

  const int tid  = threadIdx.x;
  const int wave = tid >> 6;
  const int lane = tid & 63;
  const int lr   = lane & 15;
  const int lg   = lane >> 4;        // 0..3
  const int wm   = wave >> 2;        // 0..1  (M half)
  const int wn   = wave & 3;         // 0..3  (N quarter)
  const int swl  = (lr & 7) << 3;    // read-side XOR swizzle (elements)

  // XCD-aware bijective swizzle over 512 blocks (512 % 8 == 0)
  const int bid = blockIdx.x;
  const int swz = (bid & 7) * 64 + (bid >> 3);
  const int bx  = swz & 15;          // N tile (16)
  const int by  = swz >> 4;          // M tile (32)
  const int rowBase = by * 256;
  const int colBase = bx * 256;

  // stage source: thread t covers LDS row sr, 16-B chunk (t&7); source chunk
  // is pre-swizzled so that linear LDS dest + swizzled read = identity.
  const int sr  = tid >> 3;                    // 0..63
  const int sch = (tid & 7) ^ (sr & 7);
  const uint16_t* Ag = A + (size_t)(rowBase + sr) * GK + sch * 8;
  const uint16_t* Bg = B + (size_t)(colBase + sr) * GK + sch * 8;

  f32x4 acc[8][4];
#pragma unroll
  for (int mf = 0; mf < 8; ++mf)
#pragma unroll
    for (int nf = 0; nf < 4; ++nf) acc[mf][nf] = (f32x4){0.f, 0.f, 0.f, 0.f};

  // prologue: stage tile 0 -> buf0, wait, sync
  STAGE_A(0, 0);
  STAGE_A(0, 1);
  STAGE_B(0, 0);
  STAGE_B(0, 1);
  asm volatile("s_waitcnt vmcnt(0)" ::: "memory");
  __builtin_amdgcn_s_barrier();

  bf16x8 aF[4][2], bF[2][2];

  for (int t = 0; t < NT2; ++t) {
    const uint32_t bufo = ((uint32_t)(t & 1)) * 32768u;

    // prefetch next tile -> OTHER buffer (never touches buffer being read)
    if (t + 1 < NT2) {
      STAGE_A(t + 1, 0);
      STAGE_A(t + 1, 1);
      STAGE_B(t + 1, 0);
      STAGE_B(t + 1, 1);
    }

    LDA(0); LDB(0);
    MMA(0, 0);
    LDB(1);
    MMA(0, 1);
    LDA(1);
    MMA(1, 1);
    LDB(0);          // re-read B-half0 (cheaper than +16 live VGPRs)
    MMA(1, 0);

    if (t + 1 < NT2) {
      asm volatile("s_waitcnt vmcnt(0)" ::: "memory");
      __builtin_amdgcn_s_barrier();
    }
  }

  // epilogue: C/D layout col = lane&15, row = (lane>>4)*4 + reg
  const int r0 = rowBase + wm * 128 + lg * 4;
  const int c0 = colBase + wn * 64 + lr;
#pragma unroll
  for (int mf = 0; mf < 8; ++mf)
#pragma unroll
    for (int nf = 0; nf < 4; ++nf)
#pragma unroll
      for (int e = 0; e < 4; ++e)
        C[(size_t)(r0 + mf * 16 + e) * (size_t)DF + (c0 + nf * 16)] =
            f2bf_u(acc[mf][nf][e]);

  // ---- s12: per-wave quarter partials -> LDS -> one atomic per row ----
  // Last K-tile is odd (NT2-1 = 63) -> it read buf1 (LDS 32..64 KB); the
  // first 8 KB (buf0-A) is dead and safe to reuse without a leading barrier.
  float a1v[4], a2v[4];
#pragma unroll
  for (int nf = 0; nf < 4; ++nf) {
    int col = c0 + nf * 16;
    a1v[nf] = a[col];
    a2v[nf] = a[DF + col];
  }
  float* sP = (float*)lds;   // [2][4][256] floats = 8 KB
#pragma unroll
  for (int mf = 0; mf < 8; ++mf) {
#pragma unroll
    for (int e = 0; e < 4; ++e) {
      float p1 = 0.f, p2 = 0.f;
#pragma unroll
      for (int nf = 0; nf < 4; ++nf) {
        float hv = acc[mf][nf][e];
        p1 += hv * a1v[nf];
        p2 += hv * a2v[nf];
      }
      p1 += __shfl_xor(p1, 1, 64); p1 += __shfl_xor(p1, 2, 64);
      p1 += __shfl_xor(p1, 4, 64); p1 += __shfl_xor(p1, 8, 64);
      p2 += __shfl_xor(p2, 1, 64); p2 += __shfl_xor(p2, 2, 64);
      p2 += __shfl_xor(p2, 4, 64); p2 += __shfl_xor(p2, 8, 64);
      if (lr == 0) {
        int rl = wm * 128 + lg * 4 + mf * 16 + e;   // 0..255
        sP[wn * 256 + rl]        = p1;
        sP[1024 + wn * 256 + rl] = p2;
      }
    }
  }
  __syncthreads();
  if (tid < 256) {
    float v1 = sP[tid] + sP[256 + tid] + sP[512 + tid] + sP[768 + tid];
    float v2 = sP[1024 + tid] + sP[1280 + tid] + sP[1536 + tid] + sP[1792 + tid];
    atomicAdd(&s1g[rowBase + tid], v1);
    atomicAdd(&s2g[rowBase + tid], v2);
  }
}

// --------------------------- rank + count -----------------------------------
// 128 blocks x 256 threads; 4-part j-scan with +p bank stagger (parts hit
// distinct banks). Emits pi, s2sorted, ci, and wbg/wcg at the sorted position.
__global__ __launch_bounds__(256) void rankcount_kernel(
    const float* __restrict__ s1, const float* __restrict__ s2,
    int* __restrict__ pi, float* __restrict__ s2sorted, int* __restrict__ ci,
    float* __restrict__ wbg, float* __restrict__ wcg) {
  __shared__ float ld[NB];
  const int t   = threadIdx.x;
  const int bid = blockIdx.x;
  for (int idx = t; idx < NB; idx += 256) ld[idx] = s2[idx];
  __syncthreads();
  const int i = bid * 64 + (t >> 2);
  const int p = t & 3;
  const float v   = ld[i];
  const float thr = -s1[i];
  int cr = 0, cc = 0;
  const int q0 = p * (NB / 16);          // 512 float4 per part
  for (int it = 0; it < NB / 16; it++) {
    int qq = q0 + ((it + p) & (NB / 16 - 1));   // +p stagger: distinct banks
    float4 u = ((const float4*)ld)[qq];
    int jj = qq * 4;
    cr += (u.x > v) || (u.x == v && (jj + 0) < i);
    cr += (u.y > v) || (u.y == v && (jj + 1) < i);
    cr += (u.z > v) || (u.z == v && (jj + 2) < i);
    cr += (u.w > v) || (u.w == v && (jj + 3) < i);
    cc += (u.x > thr) + (u.y > thr) + (u.z > thr) + (u.w > thr);
  }
  cr += __shfl_xor(cr, 1, 64); cr += __shfl_xor(cr, 2, 64);
  cc += __shfl_xor(cc, 1, 64); cc += __shfl_xor(cc, 2, 64);
  if (p == 0) {
    pi[cr] = i;
    s2sorted[cr] = v;
    ci[i] = cc;
    wbg[cr] = __expf(0.2f * v);
    wcg[cr] = __expf(v);
  }
}

// --------------------------- megapass1 --------------------------------------
// block 0  : Sb/Sc prefix scan + finalize (f1,f2) + bucket scan (istart) +
//            scatter (ilist) — all from rankcount outputs.
// blocks 1..512 : pass1 chunk totals (independent of block 0; no sync needed).
union MpSmem {
  struct { float pb[256]; float pc[256]; int histL[NB + 1]; int ps[256]; } mg;
  struct { int pj[CH]; float wb[CH]; float wc[CH]; } pp;
};

__global__ __launch_bounds__(256) void megapass1_kernel(
    const uint16_t* __restrict__ h, const int* __restrict__ pi,
    const float* __restrict__ wbg, const float* __restrict__ wcg,
    const float* __restrict__ s1, const int* __restrict__ ci,
    float* __restrict__ Sb, float* __restrict__ Sc,
    float* __restrict__ f1, float* __restrict__ f2,
    int* __restrict__ istart, int* __restrict__ ilist,
    float* __restrict__ Bct, float* __restrict__ Cct) {
  __shared__ MpSmem smu;
  const int t   = threadIdx.x;
  const int bid = blockIdx.x;

  if (bid == 0) {
    // ---- scan: prefix sums of wbg/wcg (already exp'd by rankcount) ----
    for (int g = t; g <= NB; g += 256) smu.mg.histL[g] = 0;
    float sb = 0.f, sc = 0.f;
    for (int c = t * 32; c < t * 32 + 32; c++) { sb += wbg[c]; sc += wcg[c]; }
    smu.mg.pb[t] = sb; smu.mg.pc[t] = sc;
    __syncthreads();
    if (t == 0) {
      float rb = 0.f, rc = 0.f;
      for (int q = 0; q < 256; q++) {
        float tb = smu.mg.pb[q], tc = smu.mg.pc[q];
        smu.mg.pb[q] = rb; smu.mg.pc[q] = rc;
        rb += tb; rc += tc;
      }
      Sb[0] = 0.f; Sc[0] = 0.f;
      Sb[NB] = rb; Sc[NB] = rc;
    }
    __syncthreads();
    {
      float rb = smu.mg.pb[t], rc = smu.mg.pc[t];
      for (int c = t * 32; c < t * 32 + 32; c++) {
        rb += wbg[c]; rc += wcg[c];
        if (c + 1 < NB) { Sb[c + 1] = rb; Sc[c + 1] = rc; }
      }
    }
    __syncthreads();
    // ---- finalize: per-i scalars + LDS histogram ----
    const float SbT = Sb[NB];
    for (int qq = 0; qq < NB / 256; qq++) {
      int i = qq * 256 + t;
      float s1i = s1[i];
      int c = ci[i];
      float q1 = __expf(0.2f * s1i), q2 = __expf(s1i);
      float l = q1 * (SbT - Sb[c]) + q2 * Sc[c];
      f1[i] = q1 / l;
      f2[i] = q2 / l;
      atomicAdd(&smu.mg.histL[c], 1);
    }
    __syncthreads();
    // ---- bucket scan -> istart; histL becomes the cursor ----
    {
      const int lo = t * 33;
      const int hi = min(lo + 33, NB + 1);
      int s = 0;
      for (int b = lo; b < hi; b++) s += smu.mg.histL[b];
      smu.mg.ps[t] = s;
      __syncthreads();
      if (t == 0) {
        int r = 0;
        for (int q = 0; q < 256; q++) {
          int v = smu.mg.ps[q]; smu.mg.ps[q] = r; r += v;
        }
      }
      __syncthreads();
      int r = smu.mg.ps[t];
      for (int b = lo; b < hi; b++) {
        istart[b] = r;
        int hv = smu.mg.histL[b];
        smu.mg.histL[b] = r;          // cursor
        r += hv;
      }
      if (t == 255) istart[NB + 1] = r;
    }
    __syncthreads();
    // ---- scatter: ilist via LDS cursor ----
    for (int qq = 0; qq < NB / 256; qq++) {
      int i = qq * 256 + t;
      int pos = atomicAdd(&smu.mg.histL[ci[i]], 1);
      ilist[pos] = i;
    }
    return;
  }

  // ---- pass1: chunk totals (blocks 1..512) ----
  const int fb = bid - 1;
  const int cb = fb & 3;
  const int k  = fb >> 2;
  if (t < CH) {
    int g = k * CH + t;
    smu.pp.pj[t] = pi[g]; smu.pp.wb[t] = wbg[g]; smu.pp.wc[t] = wcg[g];
  }
  __syncthreads();
  const int n0 = cb * 1024 + t * 4;
  float b0 = 0.f, b1 = 0.f, b2 = 0.f, b3 = 0.f;
  float c0 = 0.f, c1 = 0.f, c2 = 0.f, c3 = 0.f;
#pragma unroll 8
  for (int c = 0; c < CH; c++) {
    uint2 hv = *(const uint2*)(h + (size_t)smu.pp.pj[c] * DF + n0);
    float h0 = bfu2f((uint16_t)hv.x), h1 = bfu2f((uint16_t)(hv.x >> 16));
    float h2 = bfu2f((uint16_t)hv.y), h3 = bfu2f((uint16_t)(hv.y >> 16));
    float vb = smu.pp.wb[c], vc = smu.pp.wc[c];
    b0 += vb * h0; b1 += vb * h1; b2 += vb * h2; b3 += vb * h3;
    c0 += vc * h0; c1 += vc * h1; c2 += vc * h2; c3 += vc * h3;
  }
  *(float4*)(Bct + (size_t)k * DF + n0) = make_float4(b0, b1, b2, b3);
  *(float4*)(Cct + (size_t)k * DF + n0) = make_float4(c0, c1, c2, c3);
}

// --------------------------- chunk offset scan (per column) -----------------
__global__ __launch_bounds__(256) void boff_kernel(
    const float* __restrict__ Bct, const float* __restrict__ Cct,
    float* __restrict__ Boff, float* __restrict__ Coff) {
  __shared__ float sB[4][64], sC[4][64];
  const int t   = threadIdx.x;
  const int cl  = t & 63;
  const int seg = t >> 6;                    // 0..3 (32 chunks each)
  const int col = blockIdx.x * 64 + cl;
  float sb = 0.f, sc = 0.f;
#pragma unroll 8
  for (int u = 0; u < NCH / 4; u++) {
    int kk = seg * (NCH / 4) + u;
    sb += Bct[(size_t)kk * DF + col];
    sc += Cct[(size_t)kk * DF + col];
  }
  sB[seg][cl] = sb; sC[seg][cl] = sc;
  __syncthreads();
  float rb = 0.f, rc = 0.f;
#pragma unroll
  for (int s = 0; s < 3; s++)
    if (s < seg) { rb += sB[s][cl]; rc += sC[s][cl]; }
#pragma unroll 4
  for (int u = 0; u < NCH / 4; u++) {
    int kk = seg * (NCH / 4) + u;
    Boff[(size_t)kk * DF + col] = rb;
    Coff[(size_t)kk * DF + col] = rc;
    rb += Bct[(size_t)kk * DF + col];
    rc += Cct[(size_t)kk * DF + col];
  }
  if (seg == 3) {
    Boff[(size_t)NCH * DF + col] = rb;      // = A_n
    Coff[(size_t)NCH * DF + col] = rc;
  }
}

// --------------------------- pass2: sweep + direct emission -----------------
__global__ __launch_bounds__(256) void pass2_kernel(
    const uint16_t* __restrict__ h, const int* __restrict__ pi,
    const float* __restrict__ wbg, const float* __restrict__ wcg,
    const float* __restrict__ Boff, const float* __restrict__ Coff,
    const int* __restrict__ istart, const int* __restrict__ ilist,
    const float* __restrict__ f1, const float* __restrict__ f2,
    float* __restrict__ out) {
  __shared__ int   pj[CH];
  __shared__ float wb[CH], wc[CH];
  __shared__ int   se[CH + 2];
  const int t  = threadIdx.x;
  const int cb = blockIdx.x;
  const int k  = blockIdx.y;
  if (t < CH) {
    int g = k * CH + t;
    pj[t] = pi[g]; wb[t] = wbg[g]; wc[t] = wcg[g];
  }
  if (t < CH + 2) se[t] = istart[k * CH + t];
  __syncthreads();
  const int n0 = cb * 1024 + t * 4;
  const float4 An = *(const float4*)(Boff + (size_t)NCH * DF + n0);
  const float4 Bo = *(const float4*)(Boff + (size_t)k * DF + n0);
  const float4 Co = *(const float4*)(Coff + (size_t)k * DF + n0);
  float b0 = Bo.x, b1 = Bo.y, b2 = Bo.z, b3 = Bo.w;
  float c0 = Co.x, c1 = Co.y, c2 = Co.z, c3 = Co.w;

  if (k == 0) {   // bucket 0: boundary before any j (c_i == 0)
    for (int idx = se[0]; idx < se[1]; idx++) {
      const int i = ilist[idx];
      const float fa = f1[i];
      *(float4*)(out + (size_t)i * DF + n0) =
          make_float4(fa * An.x, fa * An.y, fa * An.z, fa * An.w);
    }
  }
  for (int c = 0; c < CH; c++) {
    uint2 hv = *(const uint2*)(h + (size_t)pj[c] * DF + n0);
    float h0 = bfu2f((uint16_t)hv.x), h1 = bfu2f((uint16_t)(hv.x >> 16));
    float h2 = bfu2f((uint16_t)hv.y), h3 = bfu2f((uint16_t)(hv.y >> 16));
    float vb = wb[c], vc = wc[c];
    b0 += vb * h0; b1 += vb * h1; b2 += vb * h2; b3 += vb * h3;
    c0 += vc * h0; c1 += vc * h1; c2 += vc * h2; c3 += vc * h3;
    const int e0 = se[c + 1], e1 = se[c + 2];
    for (int idx = e0; idx < e1; idx++) {
      const int i = ilist[idx];
      const float fa = f1[i], fb = f2[i];
      *(float4*)(out + (size_t)i * DF + n0) = make_float4(
          fa * (An.x - b0) + fb * c0, fa * (An.y - b1) + fb * c1,
          fa * (An.z - b2) + fb * c2, fa * (An.w - b3) + fb * c3);
    }
  }
}

// ---------------------------------------------------------------------------
extern "C" void kernel_launch(void* const* d_in, const int* in_sizes, int n_in,
                              void* d_out, int out_size, void* d_ws, size_t ws_size,
                              hipStream_t stream) {
  const float* x = (const float*)d_in[0];   // [8192][4096] fp32
  const float* W = (const float*)d_in[1];   // [4096][4096] fp32
  const float* a = (const float*)d_in[2];   // [8192] fp32
  float* out = (float*)d_out;               // [8192][4096] fp32

  char* ws = (char*)d_ws;
  uint16_t* h = (uint16_t*)ws;                 // 64 MB
  char* sm = ws + 67108864;
  float* s1       = (float*)(sm);
  float* s2       = (float*)(sm + 65536);
  float* s2sorted = (float*)(sm + 131072);
  int*   pi       = (int*)  (sm + 196608);
  int*   ci       = (int*)  (sm + 262144);
  float* Sb       = (float*)(sm + 327680);     // NB+1 floats
  float* Sc       = (float*)(sm + 393216);
  float* wbg      = (float*)(sm + 458752);
  float* wcg      = (float*)(sm + 524288);
  float* f1       = (float*)(sm + 589824);
  float* f2       = (float*)(sm + 655360);
  int*   istart   = (int*)  (sm + 786432);     // NB+2 ints
  int*   ilist    = (int*)  (sm + 917504);     // NB ints
  float* Bct      = (float*)(sm + 1048576);    // 2 MB
  float* Cct      = (float*)(sm + 3145728);    // 2 MB
  float* Boff     = (float*)(sm + 5242880);    // (NCH+1)*DF*4 ~ 2.02 MB
  float* Coff     = (float*)(sm + 7602176);    // ~2.02 MB (ends sm+9.96MB)
  char* base2 = ws + 67108864 + 10485760;      // staging (dead after gemm)
  uint16_t* xb = (uint16_t*)base2;             // 64 MB
  uint16_t* Wb = (uint16_t*)(base2 + 67108864);// 32 MB  (total ws ~169 MB)

  // 1: cvt x and W (+ zero s1/s2 atomic targets)
  cvt_all<<<1024, 256, 0, stream>>>(x, xb, W, Wb, s1, s2);

  // 2: GEMM + s12 epilogue (LDS-reduced, one atomic per row per block)
  gemm_nt_async<<<(NB / 256) * (DF / 256), 512, 0, stream>>>(
      xb, Wb, h, a, s1, s2);

  // 3: rank + count (reads prereduced s1/s2; emits wbg/wcg)
  rankcount_kernel<<<NB / 64, 256, 0, stream>>>(
      s1, s2, pi, s2sorted, ci, wbg, wcg);

  // 4: block0 = scan+finalize+bucketscan+scatter; blocks 1..512 = pass1
  megapass1_kernel<<<1 + (DF / 1024) * NCH, 256, 0, stream>>>(
      h, pi, wbg, wcg, s1, ci, Sb, Sc, f1, f2, istart, ilist, Bct, Cct);

  // 5: per-column chunk-offset scan
  boff_kernel<<<DF / 64, 256, 0, stream>>>(Bct, Cct, Boff, Coff);

  // 6: sweep + direct emission
  pass2_kernel<<<dim3(DF / 1024, NCH), 256, 0, stream>>>(
      h, pi, wbg, wcg, Boff, Coff, istart, ilist, f1, f2, out);
}